// Round 10
// baseline (2500.826 us; speedup 1.0000x reference)
//
#include <hip/hip_runtime.h>

// ---------------- constants ----------------
static constexpr int B = 4, N = 32768;
static constexpr int L0 = 16384, L1_ = 8192, L2_ = 4096, F = 15;

static __device__ __forceinline__ float lrelu(float x) { return x >= 0.f ? x : 0.1f * x; }

// XCD-aware block swizzle: grid is G contiguous site-groups; nwg % 8 == 0 required
// (all our grids: 512/256/128/64). Maps bid so XCD k (= bid%8 round-robin) works on
// one contiguous chunk -> each XCD's 4MB L2 holds its own lattice slice.
static __device__ __forceinline__ int xcd_swz(int bid, int nwg) {
    return (bid & 7) * (nwg >> 3) + (bid >> 3);
}

// ---------------- weight transpose (k-major for uniform scalar access) ----------------
// dst[(f*C + c)*O + o] = src[(o*C + c)*F + f]
struct TSpec { const float* src; float* dst; int O, C, Fd; };
struct TSpecs { TSpec s[5]; };

__global__ __launch_bounds__(256) void transpose_kernel(TSpecs sp) {
    TSpec t = sp.s[blockIdx.y];
    int n = t.O * t.C * t.Fd;
    int i = blockIdx.x * 256 + threadIdx.x;
    if (i >= n) return;
    int o = i / (t.C * t.Fd);
    int r = i - o * (t.C * t.Fd);
    int c = r / t.Fd, f = r - c * t.Fd;
    t.dst[(f * t.C + c) * t.O + o] = t.src[i];
}

// ---------------- per-point MLP (cb block), both pcs in one launch ----------------
__global__ __launch_bounds__(256) void cb_kernel(
    const float* __restrict__ pc1, const float* __restrict__ pc2,
    const float* __restrict__ W1, const float* __restrict__ b1,   // (32,3)
    const float* __restrict__ W2, const float* __restrict__ b2,   // (32,32)
    const float* __restrict__ W3, const float* __restrict__ b3,   // (64,32)
    float* __restrict__ feat1, float* __restrict__ feat2) {
    int g = blockIdx.x * 256 + threadIdx.x;          // over 2*B*N
    int pcid = g / (B * N);
    int r = g - pcid * (B * N);                      // b*N + m
    const float* pc = pcid ? pc2 : pc1;
    float* feat = pcid ? feat2 : feat1;
    int b = r / N, m = r - b * N;
    const float* p = pc + (size_t)b * 3 * N + m;
    float x0 = p[0], x1 = p[N], x2 = p[2 * N];
    float h1[32];
#pragma unroll
    for (int o = 0; o < 32; ++o)
        h1[o] = lrelu(W1[o * 3 + 0] * x0 + W1[o * 3 + 1] * x1 + W1[o * 3 + 2] * x2 + b1[o]);
    float h2[32];
#pragma unroll
    for (int o = 0; o < 32; ++o) {
        float a = b2[o];
#pragma unroll
        for (int c = 0; c < 32; ++c) a += W2[o * 32 + c] * h1[c];
        h2[o] = lrelu(a);
    }
    float* outp = feat + (size_t)r * 64;
#pragma unroll 1
    for (int oc = 0; oc < 16; ++oc) {
        float t[4];
#pragma unroll
        for (int j = 0; j < 4; ++j) {
            int o = oc * 4 + j;
            float a = b3[o];
#pragma unroll
            for (int c = 0; c < 32; ++c) a += W3[o * 32 + c] * h2[c];
            t[j] = lrelu(a);
        }
        float4 v; v.x = t[0]; v.y = t[1]; v.z = t[2]; v.w = t[3];
        *(float4*)(outp + oc * 4) = v;
    }
}

// ---------------- splat: one WAVE per point, lane = channel; coalesced atomics ----------------
__global__ __launch_bounds__(256) void splat_kernel(
    const float* __restrict__ el1, const float* __restrict__ bary1, const int* __restrict__ off1, const float* __restrict__ fs1,
    const float* __restrict__ el2, const float* __restrict__ bary2, const int* __restrict__ off2, const float* __restrict__ fs2,
    float* __restrict__ lat1, float* __restrict__ lat2, int M, int L) {
    int wid = (blockIdx.x * 256 + threadIdx.x) >> 6;
    int lane = threadIdx.x & 63;
    int nwaves = gridDim.x * (256 / 64);
    int total = 2 * B * M;
    for (int r2 = wid; r2 < total; r2 += nwaves) {
        int pcid = r2 / (B * M);
        int r = r2 - pcid * (B * M);
        const float* el = pcid ? el2 : el1;
        const float* bary = pcid ? bary2 : bary1;
        const int* off = pcid ? off2 : off1;
        const float* fs = pcid ? fs2 : fs1;
        float* lat = pcid ? lat2 : lat1;
        int b = r / M, m = r - b * M;
        float v0 = (lane < 4) ? el[((size_t)b * 4 + lane) * M + m]
                              : fs[(size_t)r * 64 + (lane - 4)];
        float v1 = 0.f;
        if (lane < 4) v1 = fs[(size_t)r * 64 + 60 + lane];
#pragma unroll
        for (int j = 0; j < 4; ++j) {
            float w = bary[((size_t)b * 4 + j) * M + m];   // wave-uniform broadcast
            int o = off[((size_t)b * 4 + j) * M + m];      // wave-uniform broadcast
            float* dst = lat + ((size_t)b * L + o) * 68;
            atomicAdd(dst + lane, w * v0);                 // 64 consecutive floats
            if (lane < 4) atomicAdd(dst + 64 + lane, w * v1);
        }
    }
}

// ---------------- fused blur: gather F neighbors, einsum(68x15 -> 64), lrelu, 64x64 conv, lrelu ----------
// wbT layout: [(f*68+c)*64 + o] (k-major, uniform scalar reads). out: (B, L, 64).
// amdgpu_waves_per_eu(2,2): cap occupancy at 2 waves/EU (measured occupancy is ~2 anyway)
// so the allocator can take ~256 VGPR and keep acc[64]+rv[17] in registers.
// (r9 evidence: __launch_bounds__(256,2) alone left VGPR=80 + 93MB spill writes.)
__global__ __attribute__((amdgpu_waves_per_eu(2, 2))) __launch_bounds__(256)
void blur_kernel(
    const float* __restrict__ lat1, const float* __restrict__ lat2,
    const int* __restrict__ nbr1, const int* __restrict__ nbr2,
    const float* __restrict__ wbT, const float* __restrict__ bb,
    const float* __restrict__ W1, const float* __restrict__ b1,
    float* __restrict__ out1, float* __restrict__ out2, int L) {
    int bid = xcd_swz(blockIdx.x, gridDim.x);        // XCD-local (pc,b) lattice -> L2 hits
    int g = bid * 256 + threadIdx.x;                 // over 2*B*L
    int pcid = g / (B * L);
    int r = g - pcid * (B * L);
    int b = r / L, l = r - b * L;
    const float* lat = (pcid ? lat2 : lat1) + (size_t)b * L * 68;
    const int* nbr = (pcid ? nbr2 : nbr1) + (size_t)b * F * L + l;
    int idxs[F];
#pragma unroll
    for (int f = 0; f < F; ++f) idxs[f] = nbr[f * L];
    float acc[64];
#pragma unroll
    for (int o = 0; o < 64; ++o) acc[o] = 0.f;
#pragma unroll 1
    for (int f = 0; f < F; ++f) {
        const float* row = lat + (size_t)idxs[f] * 68;
        const float* w = wbT + (size_t)(f * 68) * 64;
        float4 rv[17];
#pragma unroll
        for (int c4 = 0; c4 < 17; ++c4) rv[c4] = *(const float4*)(row + c4 * 4);
#pragma unroll
        for (int c4 = 0; c4 < 17; ++c4) {
            float4 v = rv[c4];
            const float* wk = w + c4 * 256;
#pragma unroll
            for (int o = 0; o < 64; ++o) acc[o] += wk[o] * v.x;
#pragma unroll
            for (int o = 0; o < 64; ++o) acc[o] += wk[64 + o] * v.y;
#pragma unroll
            for (int o = 0; o < 64; ++o) acc[o] += wk[128 + o] * v.z;
#pragma unroll
            for (int o = 0; o < 64; ++o) acc[o] += wk[192 + o] * v.w;
        }
    }
    float h[64];
#pragma unroll
    for (int c = 0; c < 64; ++c) h[c] = lrelu(acc[c] + bb[c]);
    float* outp = (pcid ? out2 : out1) + (size_t)r * 64;
#pragma unroll 1
    for (int oc = 0; oc < 16; ++oc) {
        float t[4];
#pragma unroll
        for (int j = 0; j < 4; ++j) {
            const float* wr = W1 + (oc * 4 + j) * 64;
            float a = b1[oc * 4 + j];
#pragma unroll
            for (int c = 0; c < 64; ++c) a += wr[c] * h[c];
            t[j] = lrelu(a);
        }
        float4 v; v.x = t[0]; v.y = t[1]; v.z = t[2]; v.w = t[3];
        *(float4*)(outp + oc * 4) = v;
    }
}

// ---------------- correlation stage A: prod = o1c * gather(o2c), einsum(64x15->32), 32x32 conv ----------
__global__ __attribute__((amdgpu_waves_per_eu(2, 2))) __launch_bounds__(256)
void corrA_kernel(
    const float* __restrict__ o1c, const float* __restrict__ o2c,
    const int* __restrict__ nbr2,
    const float* __restrict__ wcT, const float* __restrict__ bc1,
    const float* __restrict__ Wc2, const float* __restrict__ bc2,
    float* __restrict__ outc) {
    int bid = xcd_swz(blockIdx.x, gridDim.x);
    int g = bid * 256 + threadIdx.x;                 // over B*L2
    int b = g / L2_, l = g - b * L2_;
    float r1[64];
    const float* p1 = o1c + (size_t)g * 64;
#pragma unroll
    for (int c4 = 0; c4 < 16; ++c4) {
        float4 v = *(const float4*)(p1 + c4 * 4);
        r1[c4 * 4] = v.x; r1[c4 * 4 + 1] = v.y; r1[c4 * 4 + 2] = v.z; r1[c4 * 4 + 3] = v.w;
    }
    float acc[32];
#pragma unroll
    for (int o = 0; o < 32; ++o) acc[o] = 0.f;
    const float* latb = o2c + (size_t)b * L2_ * 64;
    const int* nb = nbr2 + (size_t)b * F * L2_ + l;
    int idxs[F];
#pragma unroll
    for (int f = 0; f < F; ++f) idxs[f] = nb[f * L2_];
#pragma unroll 1
    for (int f = 0; f < F; ++f) {
        const float* row = latb + (size_t)idxs[f] * 64;
        const float* w = wcT + (size_t)(f * 64) * 32;
        float4 rv[16];
#pragma unroll
        for (int c4 = 0; c4 < 16; ++c4) rv[c4] = *(const float4*)(row + c4 * 4);
#pragma unroll
        for (int c4 = 0; c4 < 16; ++c4) {
            float4 v = rv[c4];
            float p0 = r1[c4 * 4] * v.x, q1 = r1[c4 * 4 + 1] * v.y;
            float q2 = r1[c4 * 4 + 2] * v.z, q3 = r1[c4 * 4 + 3] * v.w;
            const float* wk = w + c4 * 128;
#pragma unroll
            for (int o = 0; o < 32; ++o) acc[o] += wk[o] * p0;
#pragma unroll
            for (int o = 0; o < 32; ++o) acc[o] += wk[32 + o] * q1;
#pragma unroll
            for (int o = 0; o < 32; ++o) acc[o] += wk[64 + o] * q2;
#pragma unroll
            for (int o = 0; o < 32; ++o) acc[o] += wk[96 + o] * q3;
        }
    }
    float h[32];
#pragma unroll
    for (int c = 0; c < 32; ++c) h[c] = lrelu(acc[c] + bc1[c]);
    float* outp = outc + (size_t)g * 32;
#pragma unroll 1
    for (int oc = 0; oc < 8; ++oc) {
        float t[4];
#pragma unroll
        for (int j = 0; j < 4; ++j) {
            const float* wr = Wc2 + (oc * 4 + j) * 32;
            float a = bc2[oc * 4 + j];
#pragma unroll
            for (int c = 0; c < 32; ++c) a += wr[c] * h[c];
            t[j] = lrelu(a);
        }
        float4 v; v.x = t[0]; v.y = t[1]; v.z = t[2]; v.w = t[3];
        *(float4*)(outp + oc * 4) = v;
    }
}

// ---------------- correlation stage B: gather(c), einsum(32x15->64), 64x64 conv ----------------
__global__ __attribute__((amdgpu_waves_per_eu(2, 2))) __launch_bounds__(256)
void corrB_kernel(
    const float* __restrict__ cc, const int* __restrict__ nbr1,
    const float* __restrict__ wvT, const float* __restrict__ bv1,
    const float* __restrict__ Wv2, const float* __restrict__ bv2,
    float* __restrict__ outv) {
    int bid = xcd_swz(blockIdx.x, gridDim.x);
    int g = bid * 256 + threadIdx.x;                 // over B*L2
    int b = g / L2_, l = g - b * L2_;
    float acc[64];
#pragma unroll
    for (int o = 0; o < 64; ++o) acc[o] = 0.f;
    const float* latb = cc + (size_t)b * L2_ * 32;
    const int* nb = nbr1 + (size_t)b * F * L2_ + l;
    int idxs[F];
#pragma unroll
    for (int f = 0; f < F; ++f) idxs[f] = nb[f * L2_];
#pragma unroll 1
    for (int f = 0; f < F; ++f) {
        const float* row = latb + (size_t)idxs[f] * 32;
        const float* w = wvT + (size_t)(f * 32) * 64;
        float4 rv[8];
#pragma unroll
        for (int c4 = 0; c4 < 8; ++c4) rv[c4] = *(const float4*)(row + c4 * 4);
#pragma unroll
        for (int c4 = 0; c4 < 8; ++c4) {
            float4 v = rv[c4];
            const float* wk = w + c4 * 256;
#pragma unroll
            for (int o = 0; o < 64; ++o) acc[o] += wk[o] * v.x;
#pragma unroll
            for (int o = 0; o < 64; ++o) acc[o] += wk[64 + o] * v.y;
#pragma unroll
            for (int o = 0; o < 64; ++o) acc[o] += wk[128 + o] * v.z;
#pragma unroll
            for (int o = 0; o < 64; ++o) acc[o] += wk[192 + o] * v.w;
        }
    }
    float h[64];
#pragma unroll
    for (int c = 0; c < 64; ++c) h[c] = lrelu(acc[c] + bv1[c]);
    float* outp = outv + (size_t)g * 64;
#pragma unroll 1
    for (int oc = 0; oc < 16; ++oc) {
        float t[4];
#pragma unroll
        for (int j = 0; j < 4; ++j) {
            const float* wr = Wv2 + (oc * 4 + j) * 64;
            float a = bv2[oc * 4 + j];
#pragma unroll
            for (int c = 0; c < 64; ++c) a += wr[c] * h[c];
            t[j] = lrelu(a);
        }
        float4 v; v.x = t[0]; v.y = t[1]; v.z = t[2]; v.w = t[3];
        *(float4*)(outp + oc * 4) = v;
    }
}

// ---------------- mean pooling over lattice sites (parallel partial sums + atomics) ----------------
static constexpr int MEAN_SLICES = 16;
__global__ __launch_bounds__(256) void mean_kernel(
    const float* __restrict__ o1c, const float* __restrict__ o2c,
    const float* __restrict__ vv, float* __restrict__ pooled) {
    __shared__ float red[256];
    int bi = blockIdx.x;                   // ((b*3 + arr) * SLICES) + sl
    int sl = bi % MEAN_SLICES;
    int ba = bi / MEAN_SLICES;
    int b = ba / 3, arr = ba - b * 3;
    const float* src = arr == 0 ? o1c : (arr == 1 ? o2c : vv);
    src += (size_t)b * L2_ * 64;
    int c = threadIdx.x & 63, grp = threadIdx.x >> 6;
    int rows = L2_ / MEAN_SLICES;          // 256
    int l0 = sl * rows;
    float a = 0.f;
    for (int l = l0 + grp; l < l0 + rows; l += 4) a += src[(size_t)l * 64 + c];
    red[threadIdx.x] = a;
    __syncthreads();
    if (grp == 0) {
        float s = red[c] + red[64 + c] + red[128 + c] + red[192 + c];
        atomicAdd(&pooled[b * 192 + arr * 64 + c], s * (1.f / (float)L2_));
    }
}

// ---------------- FC layer: one wave per (b, o) ----------------
__global__ __launch_bounds__(256) void fc_kernel(
    const float* __restrict__ W, const float* __restrict__ bias,
    const float* __restrict__ x, float* __restrict__ y,
    int Cin, int Cout, int relu_flag, int split_out) {
    int wid = (blockIdx.x * 256 + threadIdx.x) >> 6;
    int lane = threadIdx.x & 63;
    int b = wid / Cout, o = wid - b * Cout;
    const float* wr = W + (size_t)o * Cin;
    const float* xr = x + (size_t)b * Cin;
    float a = 0.f;
    for (int c = lane; c < Cin; c += 64) a += wr[c] * xr[c];
#pragma unroll
    for (int m = 32; m >= 1; m >>= 1) a += __shfl_xor(a, m, 64);
    if (lane == 0) {
        a += bias[o];
        if (relu_flag) a = fmaxf(a, 0.f);
        if (split_out) {
            if (o < 3) y[b * 3 + o] = a;
            else y[12 + b * 3 + (o - 3)] = a;
        } else {
            y[(size_t)b * Cout + o] = a;
        }
    }
}

// ---------------- launch ----------------
extern "C" void kernel_launch(void* const* d_in, const int* in_sizes, int n_in,
                              void* d_out, int out_size, void* d_ws, size_t ws_size,
                              hipStream_t stream) {
    const float* pc1 = (const float*)d_in[0];
    const float* pc2 = (const float*)d_in[1];
    const float* el[3][2]; const float* bary[3][2];
    const int* off[3][2]; const int* nbr[3][2];
    int base = 2;
    for (int s = 0; s < 3; ++s)
        for (int p = 0; p < 2; ++p) {
            el[s][p]   = (const float*)d_in[base + 0];
            bary[s][p] = (const float*)d_in[base + 1];
            off[s][p]  = (const int*)d_in[base + 2];
            nbr[s][p]  = (const int*)d_in[base + 3];
            base += 4;
        }
    const int* corr1 = (const int*)d_in[26];
    const int* corr2 = (const int*)d_in[27];
    const float* cbW1 = (const float*)d_in[30]; const float* cbb1 = (const float*)d_in[31];
    const float* cbW2 = (const float*)d_in[32]; const float* cbb2 = (const float*)d_in[33];
    const float* cbW3 = (const float*)d_in[34]; const float* cbb3 = (const float*)d_in[35];
    const float* bcnWb[3]; const float* bcnbb[3]; const float* bcnW1[3]; const float* bcnb1[3];
    for (int i = 0; i < 3; ++i) {
        bcnWb[i] = (const float*)d_in[36 + 4 * i];
        bcnbb[i] = (const float*)d_in[37 + 4 * i];
        bcnW1[i] = (const float*)d_in[38 + 4 * i];
        bcnb1[i] = (const float*)d_in[39 + 4 * i];
    }
    const float* Wc1 = (const float*)d_in[48]; const float* bc1 = (const float*)d_in[49];
    const float* Wc2 = (const float*)d_in[50]; const float* bc2 = (const float*)d_in[51];
    const float* Wv1 = (const float*)d_in[52]; const float* bv1 = (const float*)d_in[53];
    const float* Wv2 = (const float*)d_in[54]; const float* bv2 = (const float*)d_in[55];
    const float* fc1W = (const float*)d_in[56]; const float* fc1b = (const float*)d_in[57];
    const float* fc2W = (const float*)d_in[58]; const float* fc2b = (const float*)d_in[59];
    const float* fc3W = (const float*)d_in[60]; const float* fc3b = (const float*)d_in[61];

    float* ws = (float*)d_ws;
    size_t cur = 0;
    auto alloc = [&](size_t n) { float* p = ws + cur; cur += n; return p; };
    float* wbT[3]; for (int i = 0; i < 3; ++i) wbT[i] = alloc((size_t)64 * 68 * 15);
    float* wcT = alloc((size_t)32 * 64 * 15);
    float* wvT = alloc((size_t)64 * 32 * 15);
    float* feat1 = alloc((size_t)B * N * 64);
    float* feat2 = alloc((size_t)B * N * 64);
    float* lat = alloc((size_t)2 * B * L0 * 68);   // lat1 | lat2 (per-stage split)
    float* o1a = alloc((size_t)B * L0 * 64);
    float* o2a = alloc((size_t)B * L0 * 64);
    float* o1b = alloc((size_t)B * L1_ * 64);
    float* o2b = alloc((size_t)B * L1_ * 64);
    float* o1c = alloc((size_t)B * L2_ * 64);
    float* o2c = alloc((size_t)B * L2_ * 64);
    float* ccb = alloc((size_t)B * L2_ * 32);
    float* vvb = alloc((size_t)B * L2_ * 64);
    float* pooled = alloc((size_t)B * 192);
    float* h1 = alloc((size_t)B * 2048);
    float* h2 = alloc((size_t)B * 2048);

    // weight transposes (recomputed every call; inputs are restored each launch)
    TSpecs sp;
    sp.s[0] = { bcnWb[0], wbT[0], 64, 68, 15 };
    sp.s[1] = { bcnWb[1], wbT[1], 64, 68, 15 };
    sp.s[2] = { bcnWb[2], wbT[2], 64, 68, 15 };
    sp.s[3] = { Wc1, wcT, 32, 64, 15 };
    sp.s[4] = { Wv1, wvT, 64, 32, 15 };
    hipLaunchKernelGGL(transpose_kernel, dim3(255, 5), dim3(256), 0, stream, sp);

    cb_kernel<<<2 * B * N / 256, 256, 0, stream>>>(pc1, pc2, cbW1, cbb1, cbW2, cbb2, cbW3, cbb3,
                                                   feat1, feat2);

    const float* fsrc1 = feat1; const float* fsrc2 = feat2;
    float* outs1[3] = { o1a, o1b, o1c };
    float* outs2[3] = { o2a, o2b, o2c };
    int Ms[3] = { N, L0, L1_ };
    int Ls[3] = { L0, L1_, L2_ };
    for (int s = 0; s < 3; ++s) {
        int M = Ms[s], L = Ls[s];
        float* lat1p = lat;
        float* lat2p = lat + (size_t)B * L * 68;
        hipMemsetAsync(lat, 0, (size_t)2 * B * L * 68 * sizeof(float), stream);
        splat_kernel<<<2048, 256, 0, stream>>>(
            el[s][0], bary[s][0], off[s][0], fsrc1,
            el[s][1], bary[s][1], off[s][1], fsrc2,
            lat1p, lat2p, M, L);
        blur_kernel<<<2 * B * L / 256, 256, 0, stream>>>(
            lat1p, lat2p, nbr[s][0], nbr[s][1],
            wbT[s], bcnbb[s], bcnW1[s], bcnb1[s],
            outs1[s], outs2[s], L);
        fsrc1 = outs1[s]; fsrc2 = outs2[s];
    }

    corrA_kernel<<<B * L2_ / 256, 256, 0, stream>>>(o1c, o2c, corr2, wcT, bc1, Wc2, bc2, ccb);
    corrB_kernel<<<B * L2_ / 256, 256, 0, stream>>>(ccb, corr1, wvT, bv1, Wv2, bv2, vvb);

    hipMemsetAsync(pooled, 0, (size_t)B * 192 * sizeof(float), stream);
    mean_kernel<<<B * 3 * MEAN_SLICES, 256, 0, stream>>>(o1c, o2c, vvb, pooled);

    fc_kernel<<<B * 2048 / 4, 256, 0, stream>>>(fc1W, fc1b, pooled, h1, 192, 2048, 1, 0);
    fc_kernel<<<B * 2048 / 4, 256, 0, stream>>>(fc2W, fc2b, h1, h2, 2048, 2048, 1, 0);
    fc_kernel<<<6, 256, 0, stream>>>(fc3W, fc3b, h2, (float*)d_out, 2048, 6, 0, 1);
}

// Round 11
// 1708.714 us; speedup vs baseline: 1.4636x; 1.4636x over previous
//
#include <hip/hip_runtime.h>

// ---------------- constants ----------------
static constexpr int B = 4, N = 32768;
static constexpr int L0 = 16384, L1_ = 8192, L2_ = 4096, F = 15;

static __device__ __forceinline__ float lrelu(float x) { return x >= 0.f ? x : 0.1f * x; }

// XCD-aware block swizzle (r10: cut blur FETCH 336->39.5 MB). nwg % 8 == 0 required.
static __device__ __forceinline__ int xcd_swz(int bid, int nwg) {
    return (bid & 7) * (nwg >> 3) + (bid >> 3);
}

// ---------------- weight transpose (k-major for uniform scalar access) ----------------
// dst[(f*C + c)*O + o] = src[(o*C + c)*F + f]
struct TSpec { const float* src; float* dst; int O, C, Fd; };
struct TSpecs { TSpec s[5]; };

__global__ __launch_bounds__(256) void transpose_kernel(TSpecs sp) {
    TSpec t = sp.s[blockIdx.y];
    int n = t.O * t.C * t.Fd;
    int i = blockIdx.x * 256 + threadIdx.x;
    if (i >= n) return;
    int o = i / (t.C * t.Fd);
    int r = i - o * (t.C * t.Fd);
    int c = r / t.Fd, f = r - c * t.Fd;
    t.dst[(f * t.C + c) * t.O + o] = t.src[i];
}

// ---------------- per-point MLP (cb block), both pcs in one launch ----------------
__global__ __launch_bounds__(256) void cb_kernel(
    const float* __restrict__ pc1, const float* __restrict__ pc2,
    const float* __restrict__ W1, const float* __restrict__ b1,   // (32,3)
    const float* __restrict__ W2, const float* __restrict__ b2,   // (32,32)
    const float* __restrict__ W3, const float* __restrict__ b3,   // (64,32)
    float* __restrict__ feat1, float* __restrict__ feat2) {
    int g = blockIdx.x * 256 + threadIdx.x;          // over 2*B*N
    int pcid = g / (B * N);
    int r = g - pcid * (B * N);                      // b*N + m
    const float* pc = pcid ? pc2 : pc1;
    float* feat = pcid ? feat2 : feat1;
    int b = r / N, m = r - b * N;
    const float* p = pc + (size_t)b * 3 * N + m;
    float x0 = p[0], x1 = p[N], x2 = p[2 * N];
    float h1[32];
#pragma unroll
    for (int o = 0; o < 32; ++o)
        h1[o] = lrelu(W1[o * 3 + 0] * x0 + W1[o * 3 + 1] * x1 + W1[o * 3 + 2] * x2 + b1[o]);
    float h2[32];
#pragma unroll
    for (int o = 0; o < 32; ++o) {
        float a = b2[o];
#pragma unroll
        for (int c = 0; c < 32; ++c) a += W2[o * 32 + c] * h1[c];
        h2[o] = lrelu(a);
    }
    float* outp = feat + (size_t)r * 64;
#pragma unroll 1
    for (int oc = 0; oc < 16; ++oc) {
        float t[4];
#pragma unroll
        for (int j = 0; j < 4; ++j) {
            int o = oc * 4 + j;
            float a = b3[o];
#pragma unroll
            for (int c = 0; c < 32; ++c) a += W3[o * 32 + c] * h2[c];
            t[j] = lrelu(a);
        }
        float4 v; v.x = t[0]; v.y = t[1]; v.z = t[2]; v.w = t[3];
        *(float4*)(outp + oc * 4) = v;
    }
}

// ---------------- splat: one WAVE per point, lane = channel; coalesced atomics ----------------
__global__ __launch_bounds__(256) void splat_kernel(
    const float* __restrict__ el1, const float* __restrict__ bary1, const int* __restrict__ off1, const float* __restrict__ fs1,
    const float* __restrict__ el2, const float* __restrict__ bary2, const int* __restrict__ off2, const float* __restrict__ fs2,
    float* __restrict__ lat1, float* __restrict__ lat2, int M, int L) {
    int wid = (blockIdx.x * 256 + threadIdx.x) >> 6;
    int lane = threadIdx.x & 63;
    int nwaves = gridDim.x * (256 / 64);
    int total = 2 * B * M;
    for (int r2 = wid; r2 < total; r2 += nwaves) {
        int pcid = r2 / (B * M);
        int r = r2 - pcid * (B * M);
        const float* el = pcid ? el2 : el1;
        const float* bary = pcid ? bary2 : bary1;
        const int* off = pcid ? off2 : off1;
        const float* fs = pcid ? fs2 : fs1;
        float* lat = pcid ? lat2 : lat1;
        int b = r / M, m = r - b * M;
        float v0 = (lane < 4) ? el[((size_t)b * 4 + lane) * M + m]
                              : fs[(size_t)r * 64 + (lane - 4)];
        float v1 = 0.f;
        if (lane < 4) v1 = fs[(size_t)r * 64 + 60 + lane];
#pragma unroll
        for (int j = 0; j < 4; ++j) {
            float w = bary[((size_t)b * 4 + j) * M + m];   // wave-uniform broadcast
            int o = off[((size_t)b * 4 + j) * M + m];      // wave-uniform broadcast
            float* dst = lat + ((size_t)b * L + o) * 68;
            atomicAdd(dst + lane, w * v0);                 // 64 consecutive floats
            if (lane < 4) atomicAdd(dst + 64 + lane, w * v1);
        }
    }
}

// ---------------- fused gather-einsum-conv, 2-way output split ----------------
// Block = 128 sites x 2 output-halves. q = readfirstlane(tid>>7) so ALL weight
// addressing is provably wave-uniform -> s_load path (r8's collapse was per-lane
// weight loads from non-uniform q). Per wave: 32 outputs -> half the scalar-weight
// stream; 2x waves (4/SIMD) hide the remaining lgkmcnt stalls.
// acc[COUT/2] + rv[CIN/4] float4 ~= 110 VGPR -> no spills.
template<int CIN, int COUT, bool PROD>
__global__ __launch_bounds__(256) void gath2_kernel(
    const float* __restrict__ latA, const float* __restrict__ latB,
    const int* __restrict__ nbrA, const int* __restrict__ nbrB,
    const float* __restrict__ prodBase,
    const float* __restrict__ wT, const float* __restrict__ bias1,
    const float* __restrict__ W2, const float* __restrict__ bias2,
    float* __restrict__ outA, float* __restrict__ outB,
    int L, int perPc) {
    constexpr int NC = CIN / 4, OH = COUT / 2, HP = COUT + 1;
    __shared__ float hl[128 * HP];
    int s = threadIdx.x & 127;
    int q = __builtin_amdgcn_readfirstlane(threadIdx.x >> 7);   // wave-uniform half index
    int bid = xcd_swz(blockIdx.x, gridDim.x);
    int gsite = bid * 128 + s;
    int pcid = gsite >= perPc ? 1 : 0;
    int r = gsite - pcid * perPc;
    int b = r / L, l = r - b * L;
    const float* lat = (pcid ? latB : latA) + (size_t)b * L * CIN;
    const int* nbr = (pcid ? nbrB : nbrA) + (size_t)b * F * L + l;
    int idxs[F];
#pragma unroll
    for (int f = 0; f < F; ++f) idxs[f] = nbr[f * L];
    const float* prow = nullptr;
    if constexpr (PROD) prow = prodBase + (size_t)gsite * CIN;
    float acc[OH];
#pragma unroll
    for (int j = 0; j < OH; ++j) acc[j] = 0.f;
#pragma unroll 1
    for (int f = 0; f < F; ++f) {
        const float* row = lat + (size_t)idxs[f] * CIN;
        const float* wf = wT + (size_t)(f * CIN) * COUT + q * OH;   // scalar base
        float4 rv[NC];
#pragma unroll
        for (int c4 = 0; c4 < NC; ++c4) rv[c4] = *(const float4*)(row + c4 * 4);
        if constexpr (PROD) {
#pragma unroll
            for (int c4 = 0; c4 < NC; ++c4) {
                float4 pv = *(const float4*)(prow + c4 * 4);
                rv[c4].x *= pv.x; rv[c4].y *= pv.y; rv[c4].z *= pv.z; rv[c4].w *= pv.w;
            }
        }
#pragma unroll
        for (int c4 = 0; c4 < NC; ++c4) {
            float4 v = rv[c4];
            const float* w0 = wf + (size_t)(c4 * 4) * COUT;
#pragma unroll
            for (int j = 0; j < OH; ++j) acc[j] += w0[j] * v.x;
#pragma unroll
            for (int j = 0; j < OH; ++j) acc[j] += w0[COUT + j] * v.y;
#pragma unroll
            for (int j = 0; j < OH; ++j) acc[j] += w0[2 * COUT + j] * v.z;
#pragma unroll
            for (int j = 0; j < OH; ++j) acc[j] += w0[3 * COUT + j] * v.w;
        }
    }
    // bias + lrelu -> LDS (stride COUT+1: 2-way bank aliasing only, free)
#pragma unroll
    for (int j = 0; j < OH; ++j)
        hl[s * HP + q * OH + j] = lrelu(acc[j] + bias1[q * OH + j]);
    __syncthreads();
    // COUT x COUT conv: thread computes its half's outputs from all COUT channels
    float t[OH];
#pragma unroll
    for (int j = 0; j < OH; ++j) t[j] = bias2[q * OH + j];
#pragma unroll 1
    for (int c = 0; c < COUT; ++c) {
        float hv = hl[s * HP + c];
        const float* w2c = W2 + (size_t)(q * OH) * COUT + c;        // scalar base
#pragma unroll
        for (int j = 0; j < OH; ++j) t[j] += w2c[(size_t)j * COUT] * hv;
    }
    float* op = (pcid ? outB : outA) + (size_t)r * COUT + q * OH;
#pragma unroll
    for (int j4 = 0; j4 < OH / 4; ++j4) {
        float4 ov;
        ov.x = lrelu(t[j4 * 4 + 0]); ov.y = lrelu(t[j4 * 4 + 1]);
        ov.z = lrelu(t[j4 * 4 + 2]); ov.w = lrelu(t[j4 * 4 + 3]);
        *(float4*)(op + j4 * 4) = ov;
    }
}

// ---------------- mean pooling over lattice sites (parallel partial sums + atomics) ----------------
static constexpr int MEAN_SLICES = 16;
__global__ __launch_bounds__(256) void mean_kernel(
    const float* __restrict__ o1c, const float* __restrict__ o2c,
    const float* __restrict__ vv, float* __restrict__ pooled) {
    __shared__ float red[256];
    int bi = blockIdx.x;                   // ((b*3 + arr) * SLICES) + sl
    int sl = bi % MEAN_SLICES;
    int ba = bi / MEAN_SLICES;
    int b = ba / 3, arr = ba - b * 3;
    const float* src = arr == 0 ? o1c : (arr == 1 ? o2c : vv);
    src += (size_t)b * L2_ * 64;
    int c = threadIdx.x & 63, grp = threadIdx.x >> 6;
    int rows = L2_ / MEAN_SLICES;          // 256
    int l0 = sl * rows;
    float a = 0.f;
    for (int l = l0 + grp; l < l0 + rows; l += 4) a += src[(size_t)l * 64 + c];
    red[threadIdx.x] = a;
    __syncthreads();
    if (grp == 0) {
        float s = red[c] + red[64 + c] + red[128 + c] + red[192 + c];
        atomicAdd(&pooled[b * 192 + arr * 64 + c], s * (1.f / (float)L2_));
    }
}

// ---------------- FC layer: one wave per (b, o) ----------------
__global__ __launch_bounds__(256) void fc_kernel(
    const float* __restrict__ W, const float* __restrict__ bias,
    const float* __restrict__ x, float* __restrict__ y,
    int Cin, int Cout, int relu_flag, int split_out) {
    int wid = (blockIdx.x * 256 + threadIdx.x) >> 6;
    int lane = threadIdx.x & 63;
    int b = wid / Cout, o = wid - b * Cout;
    const float* wr = W + (size_t)o * Cin;
    const float* xr = x + (size_t)b * Cin;
    float a = 0.f;
    for (int c = lane; c < Cin; c += 64) a += wr[c] * xr[c];
#pragma unroll
    for (int m = 32; m >= 1; m >>= 1) a += __shfl_xor(a, m, 64);
    if (lane == 0) {
        a += bias[o];
        if (relu_flag) a = fmaxf(a, 0.f);
        if (split_out) {
            if (o < 3) y[b * 3 + o] = a;
            else y[12 + b * 3 + (o - 3)] = a;
        } else {
            y[(size_t)b * Cout + o] = a;
        }
    }
}

// ---------------- launch ----------------
extern "C" void kernel_launch(void* const* d_in, const int* in_sizes, int n_in,
                              void* d_out, int out_size, void* d_ws, size_t ws_size,
                              hipStream_t stream) {
    const float* pc1 = (const float*)d_in[0];
    const float* pc2 = (const float*)d_in[1];
    const float* el[3][2]; const float* bary[3][2];
    const int* off[3][2]; const int* nbr[3][2];
    int base = 2;
    for (int s = 0; s < 3; ++s)
        for (int p = 0; p < 2; ++p) {
            el[s][p]   = (const float*)d_in[base + 0];
            bary[s][p] = (const float*)d_in[base + 1];
            off[s][p]  = (const int*)d_in[base + 2];
            nbr[s][p]  = (const int*)d_in[base + 3];
            base += 4;
        }
    const int* corr1 = (const int*)d_in[26];
    const int* corr2 = (const int*)d_in[27];
    const float* cbW1 = (const float*)d_in[30]; const float* cbb1 = (const float*)d_in[31];
    const float* cbW2 = (const float*)d_in[32]; const float* cbb2 = (const float*)d_in[33];
    const float* cbW3 = (const float*)d_in[34]; const float* cbb3 = (const float*)d_in[35];
    const float* bcnWb[3]; const float* bcnbb[3]; const float* bcnW1[3]; const float* bcnb1[3];
    for (int i = 0; i < 3; ++i) {
        bcnWb[i] = (const float*)d_in[36 + 4 * i];
        bcnbb[i] = (const float*)d_in[37 + 4 * i];
        bcnW1[i] = (const float*)d_in[38 + 4 * i];
        bcnb1[i] = (const float*)d_in[39 + 4 * i];
    }
    const float* Wc1 = (const float*)d_in[48]; const float* bc1 = (const float*)d_in[49];
    const float* Wc2 = (const float*)d_in[50]; const float* bc2 = (const float*)d_in[51];
    const float* Wv1 = (const float*)d_in[52]; const float* bv1 = (const float*)d_in[53];
    const float* Wv2 = (const float*)d_in[54]; const float* bv2 = (const float*)d_in[55];
    const float* fc1W = (const float*)d_in[56]; const float* fc1b = (const float*)d_in[57];
    const float* fc2W = (const float*)d_in[58]; const float* fc2b = (const float*)d_in[59];
    const float* fc3W = (const float*)d_in[60]; const float* fc3b = (const float*)d_in[61];

    float* ws = (float*)d_ws;
    size_t cur = 0;
    auto alloc = [&](size_t n) { float* p = ws + cur; cur += n; return p; };
    float* wbT[3]; for (int i = 0; i < 3; ++i) wbT[i] = alloc((size_t)64 * 68 * 15);
    float* wcT = alloc((size_t)32 * 64 * 15);
    float* wvT = alloc((size_t)64 * 32 * 15);
    float* feat1 = alloc((size_t)B * N * 64);
    float* feat2 = alloc((size_t)B * N * 64);
    float* lat = alloc((size_t)2 * B * L0 * 68);   // lat1 | lat2 (per-stage split)
    float* o1a = alloc((size_t)B * L0 * 64);
    float* o2a = alloc((size_t)B * L0 * 64);
    float* o1b = alloc((size_t)B * L1_ * 64);
    float* o2b = alloc((size_t)B * L1_ * 64);
    float* o1c = alloc((size_t)B * L2_ * 64);
    float* o2c = alloc((size_t)B * L2_ * 64);
    float* ccb = alloc((size_t)B * L2_ * 32);
    float* vvb = alloc((size_t)B * L2_ * 64);
    float* pooled = alloc((size_t)B * 192);
    float* h1 = alloc((size_t)B * 2048);
    float* h2 = alloc((size_t)B * 2048);

    // weight transposes (recomputed every call; inputs are restored each launch)
    TSpecs sp;
    sp.s[0] = { bcnWb[0], wbT[0], 64, 68, 15 };
    sp.s[1] = { bcnWb[1], wbT[1], 64, 68, 15 };
    sp.s[2] = { bcnWb[2], wbT[2], 64, 68, 15 };
    sp.s[3] = { Wc1, wcT, 32, 64, 15 };
    sp.s[4] = { Wv1, wvT, 64, 32, 15 };
    hipLaunchKernelGGL(transpose_kernel, dim3(255, 5), dim3(256), 0, stream, sp);

    cb_kernel<<<2 * B * N / 256, 256, 0, stream>>>(pc1, pc2, cbW1, cbb1, cbW2, cbb2, cbW3, cbb3,
                                                   feat1, feat2);

    const float* fsrc1 = feat1; const float* fsrc2 = feat2;
    float* outs1[3] = { o1a, o1b, o1c };
    float* outs2[3] = { o2a, o2b, o2c };
    int Ms[3] = { N, L0, L1_ };
    int Ls[3] = { L0, L1_, L2_ };
    for (int s = 0; s < 3; ++s) {
        int M = Ms[s], L = Ls[s];
        float* lat1p = lat;
        float* lat2p = lat + (size_t)B * L * 68;
        hipMemsetAsync(lat, 0, (size_t)2 * B * L * 68 * sizeof(float), stream);
        splat_kernel<<<2048, 256, 0, stream>>>(
            el[s][0], bary[s][0], off[s][0], fsrc1,
            el[s][1], bary[s][1], off[s][1], fsrc2,
            lat1p, lat2p, M, L);
        gath2_kernel<68, 64, false><<<2 * B * L / 128, 256, 0, stream>>>(
            lat1p, lat2p, nbr[s][0], nbr[s][1], nullptr,
            wbT[s], bcnbb[s], bcnW1[s], bcnb1[s],
            outs1[s], outs2[s], L, B * L);
        fsrc1 = outs1[s]; fsrc2 = outs2[s];
    }

    // corrA: prod(o1c, gather(o2c)) -> einsum(64x15->32) -> 32x32 conv
    gath2_kernel<64, 32, true><<<B * L2_ / 128, 256, 0, stream>>>(
        o2c, o2c, corr2, corr2, o1c,
        wcT, bc1, Wc2, bc2, ccb, ccb, L2_, B * L2_);
    // corrB: gather(ccb) -> einsum(32x15->64) -> 64x64 conv
    gath2_kernel<32, 64, false><<<B * L2_ / 128, 256, 0, stream>>>(
        ccb, ccb, corr1, corr1, nullptr,
        wvT, bv1, Wv2, bv2, vvb, vvb, L2_, B * L2_);

    hipMemsetAsync(pooled, 0, (size_t)B * 192 * sizeof(float), stream);
    mean_kernel<<<B * 3 * MEAN_SLICES, 256, 0, stream>>>(o1c, o2c, vvb, pooled);

    fc_kernel<<<B * 2048 / 4, 256, 0, stream>>>(fc1W, fc1b, pooled, h1, 192, 2048, 1, 0);
    fc_kernel<<<B * 2048 / 4, 256, 0, stream>>>(fc2W, fc2b, h1, h2, 2048, 2048, 1, 0);
    fc_kernel<<<6, 256, 0, stream>>>(fc3W, fc3b, h2, (float*)d_out, 2048, 6, 0, 1);
}